// Round 6
// baseline (245.673 us; speedup 1.0000x reference)
//
#include <hip/hip_runtime.h>
#include <hip/hip_bf16.h>

typedef float f32x4 __attribute__((ext_vector_type(4)));
typedef __bf16 bf16x8 __attribute__((ext_vector_type(8)));

#define NB 4        // batch
#define NQ 4096
#define NK 4096
#define DIM 512
#define KD 64

__device__ inline bf16x8 load_cvt8(const float* __restrict__ p) {
    float4 f0 = *(const float4*)p;
    float4 f1 = *(const float4*)(p + 4);
    bf16x8 r;
    r[0] = (__bf16)f0.x; r[1] = (__bf16)f0.y; r[2] = (__bf16)f0.z; r[3] = (__bf16)f0.w;
    r[4] = (__bf16)f1.x; r[5] = (__bf16)f1.y; r[6] = (__bf16)f1.z; r[7] = (__bf16)f1.w;
    return r;
}

// ---- Q/K/V projection only (mask is consumed raw by attn now).
// blocks 0..511: Q rows (32/block, scale 1/8 folded in). blocks 512..1023: K/V rows.
__global__ __launch_bounds__(256, 4) void proj_kernel(
        const float* __restrict__ x, const float* __restrict__ buf,
        const float* __restrict__ Wq, const float* __restrict__ bq,
        const float* __restrict__ Wk, const float* __restrict__ bk,
        const float* __restrict__ Wv, const float* __restrict__ bv,
        __bf16* __restrict__ Qb, __bf16* __restrict__ Kb, __bf16* __restrict__ Vt) {
    __shared__ __align__(16) float ps[4][32][66];

    const int tid = threadIdx.x;
    const int w = tid >> 6, l = tid & 63;
    const int lr = l & 15, lk = l >> 4;
    const int rg = w >> 1, kh = w & 1;              // row-group, k-half
    const bool is_q = blockIdx.x < 512;
    const int blk = is_q ? blockIdx.x : blockIdx.x - 512;
    const long rowbase = (long)blk * 32 + rg * 16;
    const int kbase = kh * 256;

    if (is_q) {
        f32x4 acc[4] = {};
#pragma unroll 2
        for (int kk = 0; kk < 256; kk += 32) {
            bf16x8 a = load_cvt8(x + (rowbase + lr) * DIM + kbase + kk + lk * 8);
#pragma unroll
            for (int nb = 0; nb < 4; nb++) {
                bf16x8 bw = load_cvt8(Wq + (long)(nb * 16 + lr) * DIM + kbase + kk + lk * 8);
                acc[nb] = __builtin_amdgcn_mfma_f32_16x16x32_bf16(a, bw, acc[nb], 0, 0, 0);
            }
        }
#pragma unroll
        for (int nb = 0; nb < 4; nb++)
#pragma unroll
            for (int i = 0; i < 4; i++)
                ps[kh * 2][rg * 16 + lk * 4 + i][nb * 16 + lr] = acc[nb][i];
        __syncthreads();
        for (int e = tid; e < 2048; e += 256) {
            int row = e >> 6, col = e & 63;
            float v = (ps[0][row][col] + ps[2][row][col] + bq[col]) * 0.125f;  // fold 1/sqrt(KD)
            Qb[((long)blk * 32 + row) * KD + col] = (__bf16)v;
        }
    } else {
        f32x4 acck[4] = {}, accv[4] = {};
#pragma unroll 2
        for (int kk = 0; kk < 256; kk += 32) {
            bf16x8 a = load_cvt8(buf + (rowbase + lr) * DIM + kbase + kk + lk * 8);
#pragma unroll
            for (int nb = 0; nb < 4; nb++) {
                bf16x8 bwk = load_cvt8(Wk + (long)(nb * 16 + lr) * DIM + kbase + kk + lk * 8);
                bf16x8 bwv = load_cvt8(Wv + (long)(nb * 16 + lr) * DIM + kbase + kk + lk * 8);
                acck[nb] = __builtin_amdgcn_mfma_f32_16x16x32_bf16(a, bwk, acck[nb], 0, 0, 0);
                accv[nb] = __builtin_amdgcn_mfma_f32_16x16x32_bf16(a, bwv, accv[nb], 0, 0, 0);
            }
        }
#pragma unroll
        for (int nb = 0; nb < 4; nb++)
#pragma unroll
            for (int i = 0; i < 4; i++) {
                ps[kh * 2 + 0][rg * 16 + lk * 4 + i][nb * 16 + lr] = acck[nb][i];
                ps[kh * 2 + 1][rg * 16 + lk * 4 + i][nb * 16 + lr] = accv[nb][i];
            }
        __syncthreads();
        for (int e = tid; e < 2048; e += 256) {       // K: row-major, col-coalesced
            int row = e >> 6, col = e & 63;
            float v = ps[0][row][col] + ps[2][row][col] + bk[col];
            Kb[((long)blk * 32 + row) * KD + col] = (__bf16)v;
        }
        for (int e = tid; e < 2048; e += 256) {       // V: transposed store, kidx-coalesced
            int row = e & 31, col = e >> 5;
            float v = ps[1][row][col] + ps[3][row][col] + bv[col];
            long grow = (long)blk * 32 + row;
            int b = (int)(grow >> 12), kidx = (int)(grow & 4095);
            Vt[((long)b * KD + col) * NK + kidx] = (__bf16)v;
        }
    }
}

// ---- flash attention, split-K by 8, fixed-max softmax, raw-mask with 1-tile register prefetch.
// Block = 16 q rows, 8 waves; wave w owns keys [w*512, w*512+512).
__global__ __launch_bounds__(512, 4) void attn_kernel(
        const __bf16* __restrict__ Qb, const __bf16* __restrict__ Kb,
        const __bf16* __restrict__ Vt, const int* __restrict__ mask,
        float* __restrict__ out) {
    // phase 1: per-wave double P tiles: [2][16][72] bf16 at w*4608 (36864 B total)
    // phase 2 (after barrier, reuse): o_s[8][16][66] f32 (33792 B) + ml[8][16] f32 (512 B)
    __shared__ __align__(16) char smem[36864];

    const int tid = threadIdx.x;
    const int w = tid >> 6, l = tid & 63;
    const int lr = l & 15, lk = l >> 4;
    const int b = blockIdx.x >> 8;
    const int q0 = (blockIdx.x & 255) * 16;
    const int k0 = w * 512;

    const __bf16* Qp = Qb + ((long)b * NQ + q0) * KD;
    const __bf16* Kp = Kb + (long)b * NK * KD;
    const __bf16* Vp = Vt + (long)b * KD * NK;
    // per-row mask base pointers (row = lk*4+i), lane key-offset lr folded in
    const int* mrow[4];
#pragma unroll
    for (int i = 0; i < 4; i++)
        mrow[i] = mask + ((long)b * NQ + q0 + lk * 4 + i) * NK + lr;

    __bf16 (*pl0)[72] = (__bf16(*)[72])(smem + w * 4608);
    __bf16 (*pl1)[72] = (__bf16(*)[72])(smem + w * 4608 + 2304);

    bf16x8 qa[2];
#pragma unroll
    for (int ks = 0; ks < 2; ks++)
        qa[ks] = *(const bf16x8*)(Qp + (long)lr * KD + ks * 32 + lk * 8);

    f32x4 o[4] = {};
    float l_i[4] = {0.f, 0.f, 0.f, 0.f};
    int md0[16], md1[16];   // mask prefetch buffers (static indexing only)

    // prefetch first tile's mask
#pragma unroll
    for (int nb = 0; nb < 4; nb++)
#pragma unroll
        for (int i = 0; i < 4; i++)
            md0[nb * 4 + i] = mrow[i][k0 + nb * 16];

    auto mload = [&](int* md, int kt) {
#pragma unroll
        for (int nb = 0; nb < 4; nb++)
#pragma unroll
            for (int i = 0; i < 4; i++)
                md[nb * 4 + i] = mrow[i][kt + nb * 16];
    };

    auto tile = [&](int kt, __bf16 (*pl)[72], const int* md) {
        // ---- S = Q K^T  (16 q x 64 k); Q pre-scaled by 1/8
        f32x4 s[4] = {};
#pragma unroll
        for (int ks = 0; ks < 2; ks++)
#pragma unroll
            for (int nb = 0; nb < 4; nb++) {
                bf16x8 kb = *(const bf16x8*)(Kp + (long)(kt + nb * 16 + lr) * KD + ks * 32 + lk * 8);
                s[nb] = __builtin_amdgcn_mfma_f32_16x16x32_bf16(qa[ks], kb, s[nb], 0, 0, 0);
            }
        // ---- fixed-max softmax numerator: p = mask ? exp(s) : 0  (C layout: row=lk*4+i, col=nb*16+lr)
#pragma unroll
        for (int nb = 0; nb < 4; nb++)
#pragma unroll
            for (int i = 0; i < 4; i++) {
                float e = __expf(s[nb][i]);
                float p = md[nb * 4 + i] ? e : 0.0f;
                __bf16 pb = (__bf16)p;
                pl[lk * 4 + i][nb * 16 + lr] = pb;
                l_i[i] += (float)pb;       // denom from the same bf16-rounded values
            }
        // ---- O += P V
#pragma unroll
        for (int ks = 0; ks < 2; ks++) {
            bf16x8 pa = *(const bf16x8*)&pl[lr][ks * 32 + lk * 8];
#pragma unroll
            for (int nb = 0; nb < 4; nb++) {
                bf16x8 vb = *(const bf16x8*)(Vp + (long)(nb * 16 + lr) * NK + kt + ks * 32 + lk * 8);
                o[nb] = __builtin_amdgcn_mfma_f32_16x16x32_bf16(pa, vb, o[nb], 0, 0, 0);
            }
        }
    };

#pragma unroll 1
    for (int kt = k0; kt < k0 + 512; kt += 128) {
        mload(md1, kt + 64);                               // prefetch tile t+1
        tile(kt, pl0, md0);
        int nxt = (kt + 128 < k0 + 512) ? kt + 128 : k0;   // wrap on last iter (discarded)
        mload(md0, nxt);                                   // prefetch tile t+2
        tile(kt + 64, pl1, md1);
    }

    // ---- reduce denom across the 16 lr lanes (once, at the end)
#pragma unroll
    for (int i = 0; i < 4; i++) {
        float v = l_i[i];
        v += __shfl_xor(v, 1);
        v += __shfl_xor(v, 2);
        v += __shfl_xor(v, 4);
        v += __shfl_xor(v, 8);
        l_i[i] = v;
    }

    // ---- split-K merge: plain sums of (o, l)
    __syncthreads();                                  // all waves done with pl regions
    float* o_s = (float*)smem;                        // [8][16][66]
    float* ml  = (float*)(smem + 8 * 16 * 66 * 4);    // [8][16]
#pragma unroll
    for (int nb = 0; nb < 4; nb++)
#pragma unroll
        for (int i = 0; i < 4; i++)
            o_s[(w * 16 + lk * 4 + i) * 66 + nb * 16 + lr] = o[nb][i];
    if (lr == 0) {
#pragma unroll
        for (int i = 0; i < 4; i++)
            ml[w * 16 + lk * 4 + i] = l_i[i];
    }
    __syncthreads();
    for (int e = tid; e < 1024; e += 512) {
        int row = e >> 6, col = e & 63;
        float L = 0.f, O = 0.f;
#pragma unroll
        for (int ww = 0; ww < 8; ww++) {
            L += ml[ww * 16 + row];
            O += o_s[(ww * 16 + row) * 66 + col];
        }
        out[((long)b * NQ + q0 + row) * KD + col] = O / L;
    }
}

extern "C" void kernel_launch(void* const* d_in, const int* in_sizes, int n_in,
                              void* d_out, int out_size, void* d_ws, size_t ws_size,
                              hipStream_t stream) {
    const float* x      = (const float*)d_in[0];
    const float* buffer = (const float*)d_in[1];
    const int*   mask   = (const int*)d_in[2];
    const float* Wq     = (const float*)d_in[3];
    const float* bq     = (const float*)d_in[4];
    const float* Wk     = (const float*)d_in[5];
    const float* bk     = (const float*)d_in[6];
    const float* Wv     = (const float*)d_in[7];
    const float* bv     = (const float*)d_in[8];
    float* out = (float*)d_out;

    __bf16* Qb = (__bf16*)d_ws;
    __bf16* Kb = Qb + (size_t)NB * NQ * KD;
    __bf16* Vt = Kb + (size_t)NB * NK * KD;

    proj_kernel<<<dim3(1024), dim3(256), 0, stream>>>(x, buffer, Wq, bq, Wk, bk, Wv, bv, Qb, Kb, Vt);
    attn_kernel<<<dim3(NB * (NQ / 16)), dim3(512), 0, stream>>>(Qb, Kb, Vt, mask, out);
}